// Round 1
// baseline (1787.698 us; speedup 1.0000x reference)
//
#include <hip/hip_runtime.h>

#define N_NODES 50000
#define N_EDGES 800000
#define N_GRAPHS 100
#define FIN_DIM 74
#define H_DIM 256

// ---------------- degree / CSR construction ----------------

__global__ void count_kernel(const int* __restrict__ src, const int* __restrict__ dst,
                             int* __restrict__ cs, int* __restrict__ cd) {
    int e = blockIdx.x * blockDim.x + threadIdx.x;
    if (e < N_EDGES) {
        atomicAdd(&cs[src[e]], 1);
        atomicAdd(&cd[dst[e]], 1);
    }
}

__global__ void rsqrt_deg_kernel(const int* __restrict__ cs, const int* __restrict__ cd,
                                 float* __restrict__ dso, float* __restrict__ dsi) {
    int i = blockIdx.x * blockDim.x + threadIdx.x;
    if (i < N_NODES) {
        dso[i] = rsqrtf(fmaxf((float)cs[i], 1.0f));
        dsi[i] = rsqrtf(fmaxf((float)cd[i], 1.0f));
    }
}

// exclusive scan of cnt[0..n) into rp[0..n], single block of 1024 threads
__global__ void scan_kernel(const int* __restrict__ cnt, int* __restrict__ rp, int n) {
    __shared__ int wsum[16];
    __shared__ int s_carry;
    int tid = threadIdx.x;
    int lane = tid & 63, wid = tid >> 6;
    if (tid == 0) s_carry = 0;
    __syncthreads();
    for (int base = 0; base < n; base += 1024) {
        int i = base + tid;
        int v = (i < n) ? cnt[i] : 0;
        int x = v;
        #pragma unroll
        for (int ofs = 1; ofs < 64; ofs <<= 1) {
            int y = __shfl_up(x, ofs, 64);
            if (lane >= ofs) x += y;
        }
        if (lane == 63) wsum[wid] = x;
        __syncthreads();
        int wofs = 0;
        for (int w = 0; w < wid; ++w) wofs += wsum[w];
        int carry = s_carry;
        if (i < n) rp[i] = carry + wofs + x - v;
        __syncthreads();
        if (tid == 1023) s_carry = carry + wofs + x;
        __syncthreads();
    }
    if (tid == 0) rp[n] = s_carry;
}

__global__ void fill_kernel(const int* __restrict__ src, const int* __restrict__ dst,
                            const int* __restrict__ rp, int* __restrict__ fillc,
                            int* __restrict__ col) {
    int e = blockIdx.x * blockDim.x + threadIdx.x;
    if (e < N_EDGES) {
        int d = dst[e];
        int p = atomicAdd(&fillc[d], 1);
        col[rp[d] + p] = src[e];
    }
}

// ---------------- aggregation: A[n][f] = sum_{s in in(n)} h[s][f]*dso[s] ----------------

template<int F>
__global__ void aggregate_kernel(const float* __restrict__ h, const float* __restrict__ dso,
                                 const int* __restrict__ rp, const int* __restrict__ col,
                                 float* __restrict__ A) {
    int n = blockIdx.x;
    int f = threadIdx.x;
    int beg = rp[n], end = rp[n + 1];
    if (f < F) {
        float acc = 0.0f;
        int j = beg;
        for (; j + 1 < end; j += 2) {
            int s0 = col[j], s1 = col[j + 1];
            float d0 = dso[s0], d1 = dso[s1];
            float h0 = h[(size_t)s0 * F + f];
            float h1 = h[(size_t)s1 * F + f];
            acc += h0 * d0 + h1 * d1;
        }
        if (j < end) {
            int s0 = col[j];
            acc += h[(size_t)s0 * F + f] * dso[s0];
        }
        A[(size_t)n * F + f] = acc;
    }
}

// ---------------- C[m][j] = relu((A@W)[m][j]*dsi[m] + bias[j]) ----------------
// A: [M x K], W: [K x 256], C: [M x 256]. 128x128 tile, BK=8, 8x8/thread.

template<int K>
__global__ __launch_bounds__(256) void gemm_bias_relu(
        const float* __restrict__ A, const float* __restrict__ W,
        const float* __restrict__ bias, const float* __restrict__ dsi,
        float* __restrict__ C, int M) {
    __shared__ float As[8][132];
    __shared__ float Ws[8][128];
    int bm = blockIdx.y * 128;
    int bn = blockIdx.x * 128;
    int tid = threadIdx.x;
    int tx = tid & 15, ty = tid >> 4;
    float acc[8][8] = {};

    for (int k0 = 0; k0 < K; k0 += 8) {
        #pragma unroll
        for (int i = 0; i < 4; ++i) {
            int e = tid + i * 256;
            int m = e >> 3, k = e & 7;
            int gm = bm + m, gk = k0 + k;
            As[k][m] = (gm < M && gk < K) ? A[(size_t)gm * K + gk] : 0.0f;
        }
        #pragma unroll
        for (int i = 0; i < 4; ++i) {
            int e = tid + i * 256;
            int k = e >> 7, n = e & 127;
            int gk = k0 + k;
            Ws[k][n] = (gk < K) ? W[(size_t)gk * H_DIM + bn + n] : 0.0f;
        }
        __syncthreads();
        #pragma unroll
        for (int kk = 0; kk < 8; ++kk) {
            float a[8], b[8];
            #pragma unroll
            for (int i = 0; i < 8; ++i) a[i] = As[kk][ty * 8 + i];
            #pragma unroll
            for (int i = 0; i < 8; ++i) b[i] = Ws[kk][tx * 8 + i];
            #pragma unroll
            for (int i = 0; i < 8; ++i)
                #pragma unroll
                for (int j = 0; j < 8; ++j)
                    acc[i][j] += a[i] * b[j];
        }
        __syncthreads();
    }

    #pragma unroll
    for (int i = 0; i < 8; ++i) {
        int gm = bm + ty * 8 + i;
        if (gm >= M) continue;
        float di = dsi[gm];
        #pragma unroll
        for (int j = 0; j < 8; ++j) {
            int gn = bn + tx * 8 + j;
            C[(size_t)gm * H_DIM + gn] = fmaxf(acc[i][j] * di + bias[gn], 0.0f);
        }
    }
}

// ---------------- pooling: pool[g][f] += h[n][f] for gid[n]==g (gid sorted) ----------------

__global__ void pool_kernel(const float* __restrict__ h, const int* __restrict__ gid,
                            float* __restrict__ pool) {
    int n0 = blockIdx.x * 64;
    int f = threadIdx.x;
    int end = min(n0 + 64, N_NODES);
    float acc = 0.0f;
    int gcur = gid[n0];
    for (int i = n0; i < end; ++i) {
        int g = gid[i];
        if (g != gcur) {
            atomicAdd(&pool[(size_t)gcur * H_DIM + f], acc);
            acc = 0.0f;
            gcur = g;
        }
        acc += h[(size_t)i * H_DIM + f];
    }
    atomicAdd(&pool[(size_t)gcur * H_DIM + f], acc);
}

// ---------------- final MLP: out[g] = relu([pl,pr]@Wf1+bf1)@Wf2 + bf2 ----------------

__global__ __launch_bounds__(256) void mlp_kernel(
        const float* __restrict__ pl, const float* __restrict__ pr,
        const float* __restrict__ Wf1, const float* __restrict__ bf1,
        const float* __restrict__ Wf2, const float* __restrict__ bf2,
        float* __restrict__ out) {
    __shared__ float z[512];
    __shared__ float red[256];
    int g = blockIdx.x, tid = threadIdx.x;
    z[tid] = pl[(size_t)g * H_DIM + tid];
    z[tid + 256] = pr[(size_t)g * H_DIM + tid];
    __syncthreads();
    float t = bf1[tid];
    #pragma unroll 8
    for (int k = 0; k < 512; ++k) t += z[k] * Wf1[(size_t)k * H_DIM + tid];
    t = fmaxf(t, 0.0f);
    red[tid] = t * Wf2[tid];
    __syncthreads();
    for (int ofs = 128; ofs > 0; ofs >>= 1) {
        if (tid < ofs) red[tid] += red[tid + ofs];
        __syncthreads();
    }
    if (tid == 0) out[g] = red[0] + bf2[0];
}

// ---------------- driver ----------------

extern "C" void kernel_launch(void* const* d_in, const int* in_sizes, int n_in,
                              void* d_out, int out_size, void* d_ws, size_t ws_size,
                              hipStream_t stream) {
    const float* xl   = (const float*)d_in[0];
    const float* xr   = (const float*)d_in[1];
    const int* src_l  = (const int*)d_in[2];
    const int* dst_l  = (const int*)d_in[3];
    const int* src_r  = (const int*)d_in[4];
    const int* dst_r  = (const int*)d_in[5];
    const int* gid_l  = (const int*)d_in[6];
    const int* gid_r  = (const int*)d_in[7];
    const float* W0   = (const float*)d_in[8];
    const float* b0   = (const float*)d_in[9];
    const float* W1   = (const float*)d_in[10];
    const float* b1   = (const float*)d_in[11];
    const float* W2   = (const float*)d_in[12];
    const float* b2   = (const float*)d_in[13];
    const float* Wf1  = (const float*)d_in[14];
    const float* bf1  = (const float*)d_in[15];
    const float* Wf2  = (const float*)d_in[16];
    const float* bf2  = (const float*)d_in[17];
    float* out = (float*)d_out;

    // workspace carve-up (aligned to 256B)
    size_t off = 0;
    auto carve = [&](size_t bytes) {
        void* p = (char*)d_ws + off;
        off += (bytes + 255) & ~(size_t)255;
        return p;
    };
    float* bufA   = (float*)carve((size_t)N_NODES * H_DIM * 4);   // aggregate output
    float* bufH   = (float*)carve((size_t)N_NODES * H_DIM * 4);   // layer output
    int*   cnt_s  = (int*)carve((size_t)N_NODES * 4);
    int*   cnt_d  = (int*)carve((size_t)N_NODES * 4);
    float* dso    = (float*)carve((size_t)N_NODES * 4);
    float* dsi    = (float*)carve((size_t)N_NODES * 4);
    int*   rp     = (int*)carve((size_t)(N_NODES + 1) * 4);
    int*   fillc  = (int*)carve((size_t)N_NODES * 4);
    int*   col    = (int*)carve((size_t)N_EDGES * 4);
    float* pool_l = (float*)carve((size_t)N_GRAPHS * H_DIM * 4);
    float* pool_r = (float*)carve((size_t)N_GRAPHS * H_DIM * 4);
    (void)ws_size; (void)in_sizes; (void)n_in; (void)out_size;

    hipMemsetAsync(pool_l, 0, (size_t)N_GRAPHS * H_DIM * 4, stream);
    hipMemsetAsync(pool_r, 0, (size_t)N_GRAPHS * H_DIM * 4, stream);

    const int EB = 256, EG = (N_EDGES + EB - 1) / EB;
    const int NB = 256, NG = (N_NODES + NB - 1) / NB;
    dim3 ggrid(H_DIM / 128, (N_NODES + 127) / 128);

    const float* xs[2]    = { xl, xr };
    const int* srcs[2]    = { src_l, src_r };
    const int* dsts[2]    = { dst_l, dst_r };
    const int* gids[2]    = { gid_l, gid_r };
    float* pools[2]       = { pool_l, pool_r };

    for (int s = 0; s < 2; ++s) {
        // CSR + degree norms for this stream
        hipMemsetAsync(cnt_s, 0, (size_t)N_NODES * 4, stream);
        hipMemsetAsync(cnt_d, 0, (size_t)N_NODES * 4, stream);
        hipMemsetAsync(fillc, 0, (size_t)N_NODES * 4, stream);
        count_kernel<<<EG, EB, 0, stream>>>(srcs[s], dsts[s], cnt_s, cnt_d);
        rsqrt_deg_kernel<<<NG, NB, 0, stream>>>(cnt_s, cnt_d, dso, dsi);
        scan_kernel<<<1, 1024, 0, stream>>>(cnt_d, rp, N_NODES);
        fill_kernel<<<EG, EB, 0, stream>>>(srcs[s], dsts[s], rp, fillc, col);

        // layer 0 (aggregate-first over 74 features)
        aggregate_kernel<FIN_DIM><<<N_NODES, 128, 0, stream>>>(xs[s], dso, rp, col, bufA);
        gemm_bias_relu<FIN_DIM><<<ggrid, 256, 0, stream>>>(bufA, W0, b0, dsi, bufH, N_NODES);
        // layer 1
        aggregate_kernel<H_DIM><<<N_NODES, 256, 0, stream>>>(bufH, dso, rp, col, bufA);
        gemm_bias_relu<H_DIM><<<ggrid, 256, 0, stream>>>(bufA, W1, b1, dsi, bufH, N_NODES);
        // layer 2
        aggregate_kernel<H_DIM><<<N_NODES, 256, 0, stream>>>(bufH, dso, rp, col, bufA);
        gemm_bias_relu<H_DIM><<<ggrid, 256, 0, stream>>>(bufA, W2, b2, dsi, bufH, N_NODES);

        // sum-pool per graph
        pool_kernel<<<(N_NODES + 63) / 64, 256, 0, stream>>>(bufH, gids[s], pools[s]);
    }

    mlp_kernel<<<N_GRAPHS, 256, 0, stream>>>(pool_l, pool_r, Wf1, bf1, Wf2, bf2, out);
}

// Round 2
// 1379.035 us; speedup vs baseline: 1.2963x; 1.2963x over previous
//
#include <hip/hip_runtime.h>

#define N_NODES 50000
#define N_EDGES 800000
#define N_GRAPHS 100
#define FIN_DIM 74
#define H_DIM 256
#define K0PAD 96

typedef float f32x4 __attribute__((ext_vector_type(4)));
typedef unsigned short us4 __attribute__((ext_vector_type(4)));
typedef unsigned short us8 __attribute__((ext_vector_type(8)));
typedef __bf16 bf16x8 __attribute__((ext_vector_type(8)));

__device__ __forceinline__ unsigned short f2bf(float x) {
    unsigned u = __builtin_bit_cast(unsigned, x);
    u += 0x7fff + ((u >> 16) & 1);
    return (unsigned short)(u >> 16);
}
__device__ __forceinline__ float bf2f(unsigned short h) {
    return __builtin_bit_cast(float, (unsigned)h << 16);
}

// ---------------- degree / CSR construction ----------------

__global__ void count_kernel(const int* __restrict__ src, const int* __restrict__ dst,
                             int* __restrict__ cs, int* __restrict__ cd) {
    int e = blockIdx.x * blockDim.x + threadIdx.x;
    if (e < N_EDGES) {
        atomicAdd(&cs[src[e]], 1);
        atomicAdd(&cd[dst[e]], 1);
    }
}

__global__ void rsqrt_deg_kernel(const int* __restrict__ cs, const int* __restrict__ cd,
                                 float* __restrict__ dso, float* __restrict__ dsi) {
    int i = blockIdx.x * blockDim.x + threadIdx.x;
    if (i < N_NODES) {
        dso[i] = rsqrtf(fmaxf((float)cs[i], 1.0f));
        dsi[i] = rsqrtf(fmaxf((float)cd[i], 1.0f));
    }
}

// exclusive scan of cnt[0..n) into rp[0..n], single block of 1024 threads
__global__ void scan_kernel(const int* __restrict__ cnt, int* __restrict__ rp, int n) {
    __shared__ int wsum[16];
    __shared__ int s_carry;
    int tid = threadIdx.x;
    int lane = tid & 63, wid = tid >> 6;
    if (tid == 0) s_carry = 0;
    __syncthreads();
    for (int base = 0; base < n; base += 1024) {
        int i = base + tid;
        int v = (i < n) ? cnt[i] : 0;
        int x = v;
        #pragma unroll
        for (int ofs = 1; ofs < 64; ofs <<= 1) {
            int y = __shfl_up(x, ofs, 64);
            if (lane >= ofs) x += y;
        }
        if (lane == 63) wsum[wid] = x;
        __syncthreads();
        int wofs = 0;
        for (int w = 0; w < wid; ++w) wofs += wsum[w];
        int carry = s_carry;
        if (i < n) rp[i] = carry + wofs + x - v;
        __syncthreads();
        if (tid == 1023) s_carry = carry + wofs + x;
        __syncthreads();
    }
    if (tid == 0) rp[n] = s_carry;
}

__global__ void fill_kernel(const int* __restrict__ src, const int* __restrict__ dst,
                            const int* __restrict__ rp, int* __restrict__ fillc,
                            int* __restrict__ col) {
    int e = blockIdx.x * blockDim.x + threadIdx.x;
    if (e < N_EDGES) {
        int d = dst[e];
        int p = atomicAdd(&fillc[d], 1);
        col[rp[d] + p] = src[e];
    }
}

// ---------------- aggregation: A[n][f] = sum_{s in in(n)} h[s][f]*dso[s] ----------------
// F = real feature count, LDI = input row stride, LDO = output row stride
// (cols F..LDO-1 of output are zero-filled padding)

template<int F, int LDI, int LDO>
__global__ void aggregate_kernel(const float* __restrict__ h, const float* __restrict__ dso,
                                 const int* __restrict__ rp, const int* __restrict__ col,
                                 float* __restrict__ A) {
    int n = blockIdx.x;
    int f = threadIdx.x;
    int beg = rp[n], end = rp[n + 1];
    if (f < F) {
        float acc = 0.0f;
        int j = beg;
        for (; j + 1 < end; j += 2) {
            int s0 = col[j], s1 = col[j + 1];
            float d0 = dso[s0], d1 = dso[s1];
            float h0 = h[(size_t)s0 * LDI + f];
            float h1 = h[(size_t)s1 * LDI + f];
            acc += h0 * d0 + h1 * d1;
        }
        if (j < end) {
            int s0 = col[j];
            acc += h[(size_t)s0 * LDI + f] * dso[s0];
        }
        A[(size_t)n * LDO + f] = acc;
    } else if (f < LDO) {
        A[(size_t)n * LDO + f] = 0.0f;
    }
}

// ---------------- MFMA GEMM: C[m][j] = relu((A@W)[m][j]*dsi[m] + bias[j]) ----------------
// A: [M x K] f32 (K padded to mult of 32, row stride K), W: [KW x 256] f32, C: [M x 256] f32.
// Split precision: A = Ah + Al (bf16), W = Wh + Wl; acc += Al*Wh + Ah*Wl + Ah*Wh.
// 128x128 tile, BK=32, 4 waves of 64x64, 16x16x32 bf16 MFMA.

template<int K, int KW>
__global__ __launch_bounds__(256, 2) void gemm_mfma(
        const float* __restrict__ A, const float* __restrict__ W,
        const float* __restrict__ bias, const float* __restrict__ dsi,
        float* __restrict__ C, int M) {
    __shared__ unsigned short Ah[128][32];
    __shared__ unsigned short Al[128][32];
    __shared__ unsigned short Bh[128][36];   // [col][k], padded stride vs bank conflicts
    __shared__ unsigned short Bl[128][36];

    int tid = threadIdx.x;
    int lane = tid & 63, wid = tid >> 6;
    int wm = (wid >> 1) * 64, wn = (wid & 1) * 64;
    int bm = blockIdx.y * 128, bn = blockIdx.x * 128;

    f32x4 acc[4][4] = {};

    int r0 = wm + (lane & 15);
    int c0 = wn + (lane & 15);
    int kA = (lane >> 4) * 8;

    for (int k0 = 0; k0 < K; k0 += 32) {
        // ---- stage A tile (128x32), split hi/lo ----
        #pragma unroll
        for (int i = 0; i < 4; ++i) {
            int q = tid + i * 256;
            int row = q >> 3, k4 = (q & 7) * 4;
            int gm = bm + row;
            f32x4 v = {0.f, 0.f, 0.f, 0.f};
            if (gm < M) v = *(const f32x4*)(A + (size_t)gm * K + k0 + k4);
            us4 h, l;
            #pragma unroll
            for (int j = 0; j < 4; ++j) {
                unsigned short hh = f2bf(v[j]);
                h[j] = hh;
                l[j] = f2bf(v[j] - bf2f(hh));
            }
            *(us4*)&Ah[row][k4] = h;
            *(us4*)&Al[row][k4] = l;
        }
        // ---- stage B tile (32x128 -> transposed [col][k]), split hi/lo ----
        {
            int col = tid & 127, kg = tid >> 7;
            us4 h[4], l[4];
            #pragma unroll
            for (int g = 0; g < 4; ++g) {
                #pragma unroll
                for (int j = 0; j < 4; ++j) {
                    int gk = k0 + kg * 16 + g * 4 + j;
                    float w = 0.f;
                    if (gk < KW) w = W[(size_t)gk * H_DIM + bn + col];
                    unsigned short hh = f2bf(w);
                    h[g][j] = hh;
                    l[g][j] = f2bf(w - bf2f(hh));
                }
            }
            #pragma unroll
            for (int g = 0; g < 4; ++g) {
                *(us4*)&Bh[col][kg * 16 + g * 4] = h[g];
                *(us4*)&Bl[col][kg * 16 + g * 4] = l[g];
            }
        }
        __syncthreads();

        // ---- fragments ----
        bf16x8 ah[4], al[4], bh[4], bl[4];
        #pragma unroll
        for (int m = 0; m < 4; ++m) {
            ah[m] = __builtin_bit_cast(bf16x8, *(const us8*)&Ah[r0 + m * 16][kA]);
            al[m] = __builtin_bit_cast(bf16x8, *(const us8*)&Al[r0 + m * 16][kA]);
        }
        #pragma unroll
        for (int n = 0; n < 4; ++n) {
            us4 x0 = *(const us4*)&Bh[c0 + n * 16][kA];
            us4 x1 = *(const us4*)&Bh[c0 + n * 16][kA + 4];
            us8 x;
            x[0] = x0[0]; x[1] = x0[1]; x[2] = x0[2]; x[3] = x0[3];
            x[4] = x1[0]; x[5] = x1[1]; x[6] = x1[2]; x[7] = x1[3];
            bh[n] = __builtin_bit_cast(bf16x8, x);
            us4 y0 = *(const us4*)&Bl[c0 + n * 16][kA];
            us4 y1 = *(const us4*)&Bl[c0 + n * 16][kA + 4];
            us8 y;
            y[0] = y0[0]; y[1] = y0[1]; y[2] = y0[2]; y[3] = y0[3];
            y[4] = y1[0]; y[5] = y1[1]; y[6] = y1[2]; y[7] = y1[3];
            bl[n] = __builtin_bit_cast(bf16x8, y);
        }

        #pragma unroll
        for (int m = 0; m < 4; ++m)
            #pragma unroll
            for (int n = 0; n < 4; ++n) {
                acc[m][n] = __builtin_amdgcn_mfma_f32_16x16x32_bf16(al[m], bh[n], acc[m][n], 0, 0, 0);
                acc[m][n] = __builtin_amdgcn_mfma_f32_16x16x32_bf16(ah[m], bl[n], acc[m][n], 0, 0, 0);
                acc[m][n] = __builtin_amdgcn_mfma_f32_16x16x32_bf16(ah[m], bh[n], acc[m][n], 0, 0, 0);
            }
        __syncthreads();
    }

    // ---- epilogue: *dsi + bias, relu ----
    int rowq = (lane >> 4) * 4;
    #pragma unroll
    for (int n = 0; n < 4; ++n) {
        int gn = bn + wn + n * 16 + (lane & 15);
        float bv = bias[gn];
        #pragma unroll
        for (int m = 0; m < 4; ++m) {
            #pragma unroll
            for (int j = 0; j < 4; ++j) {
                int gm = bm + wm + m * 16 + rowq + j;
                if (gm < M) {
                    C[(size_t)gm * H_DIM + gn] = fmaxf(acc[m][n][j] * dsi[gm] + bv, 0.0f);
                }
            }
        }
    }
}

// ---------------- pooling: pool[g][f] += h[n][f] for gid[n]==g (gid sorted) ----------------

__global__ void pool_kernel(const float* __restrict__ h, const int* __restrict__ gid,
                            float* __restrict__ pool) {
    int n0 = blockIdx.x * 64;
    int f = threadIdx.x;
    int end = min(n0 + 64, N_NODES);
    float acc = 0.0f;
    int gcur = gid[n0];
    for (int i = n0; i < end; ++i) {
        int g = gid[i];
        if (g != gcur) {
            atomicAdd(&pool[(size_t)gcur * H_DIM + f], acc);
            acc = 0.0f;
            gcur = g;
        }
        acc += h[(size_t)i * H_DIM + f];
    }
    atomicAdd(&pool[(size_t)gcur * H_DIM + f], acc);
}

// ---------------- final MLP ----------------

__global__ __launch_bounds__(256) void mlp_kernel(
        const float* __restrict__ pl, const float* __restrict__ pr,
        const float* __restrict__ Wf1, const float* __restrict__ bf1,
        const float* __restrict__ Wf2, const float* __restrict__ bf2,
        float* __restrict__ out) {
    __shared__ float z[512];
    __shared__ float red[256];
    int g = blockIdx.x, tid = threadIdx.x;
    z[tid] = pl[(size_t)g * H_DIM + tid];
    z[tid + 256] = pr[(size_t)g * H_DIM + tid];
    __syncthreads();
    float t = bf1[tid];
    #pragma unroll 8
    for (int k = 0; k < 512; ++k) t += z[k] * Wf1[(size_t)k * H_DIM + tid];
    t = fmaxf(t, 0.0f);
    red[tid] = t * Wf2[tid];
    __syncthreads();
    for (int ofs = 128; ofs > 0; ofs >>= 1) {
        if (tid < ofs) red[tid] += red[tid + ofs];
        __syncthreads();
    }
    if (tid == 0) out[g] = red[0] + bf2[0];
}

// ---------------- driver ----------------

extern "C" void kernel_launch(void* const* d_in, const int* in_sizes, int n_in,
                              void* d_out, int out_size, void* d_ws, size_t ws_size,
                              hipStream_t stream) {
    const float* xl   = (const float*)d_in[0];
    const float* xr   = (const float*)d_in[1];
    const int* src_l  = (const int*)d_in[2];
    const int* dst_l  = (const int*)d_in[3];
    const int* src_r  = (const int*)d_in[4];
    const int* dst_r  = (const int*)d_in[5];
    const int* gid_l  = (const int*)d_in[6];
    const int* gid_r  = (const int*)d_in[7];
    const float* W0   = (const float*)d_in[8];
    const float* b0   = (const float*)d_in[9];
    const float* W1   = (const float*)d_in[10];
    const float* b1   = (const float*)d_in[11];
    const float* W2   = (const float*)d_in[12];
    const float* b2   = (const float*)d_in[13];
    const float* Wf1  = (const float*)d_in[14];
    const float* bf1  = (const float*)d_in[15];
    const float* Wf2  = (const float*)d_in[16];
    const float* bf2  = (const float*)d_in[17];
    float* out = (float*)d_out;

    size_t off = 0;
    auto carve = [&](size_t bytes) {
        void* p = (char*)d_ws + off;
        off += (bytes + 255) & ~(size_t)255;
        return p;
    };
    float* bufA   = (float*)carve((size_t)N_NODES * H_DIM * 4);
    float* bufH   = (float*)carve((size_t)N_NODES * H_DIM * 4);
    int*   cnt_s  = (int*)carve((size_t)N_NODES * 4);
    int*   cnt_d  = (int*)carve((size_t)N_NODES * 4);
    float* dso    = (float*)carve((size_t)N_NODES * 4);
    float* dsi    = (float*)carve((size_t)N_NODES * 4);
    int*   rp     = (int*)carve((size_t)(N_NODES + 1) * 4);
    int*   fillc  = (int*)carve((size_t)N_NODES * 4);
    int*   col    = (int*)carve((size_t)N_EDGES * 4);
    float* pool_l = (float*)carve((size_t)N_GRAPHS * H_DIM * 4);
    float* pool_r = (float*)carve((size_t)N_GRAPHS * H_DIM * 4);
    (void)ws_size; (void)in_sizes; (void)n_in; (void)out_size;

    hipMemsetAsync(pool_l, 0, (size_t)N_GRAPHS * H_DIM * 4, stream);
    hipMemsetAsync(pool_r, 0, (size_t)N_GRAPHS * H_DIM * 4, stream);

    const int EB = 256, EG = (N_EDGES + EB - 1) / EB;
    const int NB = 256, NG = (N_NODES + NB - 1) / NB;
    dim3 ggrid(H_DIM / 128, (N_NODES + 127) / 128);

    const float* xs[2]    = { xl, xr };
    const int* srcs[2]    = { src_l, src_r };
    const int* dsts[2]    = { dst_l, dst_r };
    const int* gids[2]    = { gid_l, gid_r };
    float* pools[2]       = { pool_l, pool_r };

    for (int s = 0; s < 2; ++s) {
        hipMemsetAsync(cnt_s, 0, (size_t)N_NODES * 4, stream);
        hipMemsetAsync(cnt_d, 0, (size_t)N_NODES * 4, stream);
        hipMemsetAsync(fillc, 0, (size_t)N_NODES * 4, stream);
        count_kernel<<<EG, EB, 0, stream>>>(srcs[s], dsts[s], cnt_s, cnt_d);
        rsqrt_deg_kernel<<<NG, NB, 0, stream>>>(cnt_s, cnt_d, dso, dsi);
        scan_kernel<<<1, 1024, 0, stream>>>(cnt_d, rp, N_NODES);
        fill_kernel<<<EG, EB, 0, stream>>>(srcs[s], dsts[s], rp, fillc, col);

        // layer 0: aggregate 74 feats (pad to 96), then MFMA GEMM K=96 (KW=74)
        aggregate_kernel<FIN_DIM, FIN_DIM, K0PAD><<<N_NODES, 128, 0, stream>>>(xs[s], dso, rp, col, bufA);
        gemm_mfma<K0PAD, FIN_DIM><<<ggrid, 256, 0, stream>>>(bufA, W0, b0, dsi, bufH, N_NODES);
        // layer 1
        aggregate_kernel<H_DIM, H_DIM, H_DIM><<<N_NODES, 256, 0, stream>>>(bufH, dso, rp, col, bufA);
        gemm_mfma<H_DIM, H_DIM><<<ggrid, 256, 0, stream>>>(bufA, W1, b1, dsi, bufH, N_NODES);
        // layer 2
        aggregate_kernel<H_DIM, H_DIM, H_DIM><<<N_NODES, 256, 0, stream>>>(bufH, dso, rp, col, bufA);
        gemm_mfma<H_DIM, H_DIM><<<ggrid, 256, 0, stream>>>(bufA, W2, b2, dsi, bufH, N_NODES);

        pool_kernel<<<(N_NODES + 63) / 64, 256, 0, stream>>>(bufH, gids[s], pools[s]);
    }

    mlp_kernel<<<N_GRAPHS, 256, 0, stream>>>(pool_l, pool_r, Wf1, bf1, Wf2, bf2, out);
}